// Round 6
// baseline (1301.242 us; speedup 1.0000x reference)
//
#include <hip/hip_runtime.h>
#include <hip/hip_bf16.h>
#include <cstdint>
#include <cstddef>

#define N_TOKENS  4096
#define DIM       2048
#define N_EXPERTS 32
#define TOPK      4
#define INTER     1408
#define TWO_INTER 2816
#define CAP       1024
#define T_ASSIGN  (N_TOKENS*TOPK)

typedef __attribute__((ext_vector_type(8))) short short8;
typedef __attribute__((ext_vector_type(4))) float f32x4;

__device__ __forceinline__ unsigned pack_bf16(float a, float b) {
  unsigned ua = __builtin_bit_cast(unsigned, a);
  unsigned ub = __builtin_bit_cast(unsigned, b);
  ua = (ua + 0x8000u) >> 16;
  ub = (ub + 0x8000u) & 0xFFFF0000u;
  return ua | ub;
}
__device__ __forceinline__ unsigned short bf16_1(float a) {
  return (unsigned short)((__builtin_bit_cast(unsigned, a) + 0x8000u) >> 16);
}

__device__ __forceinline__ void gl_lds16(const void* g, void* l) {
  __builtin_amdgcn_global_load_lds(
      (const __attribute__((address_space(1))) unsigned int*)g,
      (__attribute__((address_space(3))) unsigned int*)l, 16, 0, 0);
}

// ---------------- routing build ----------------
__global__ void k_build(const int* __restrict__ tmask, const float* __restrict__ w,
                        const int* __restrict__ idx, int* __restrict__ counts,
                        int* __restrict__ tok, float* __restrict__ pb) {
  int i = blockIdx.x * 256 + threadIdx.x;
  if (i >= T_ASSIGN) return;
  int t = i >> 2;
  int e = idx[i];
  if (e < 0 || e >= N_EXPERTS) return;
  if (tmask[t] == 0) return;
  int r = atomicAdd(&counts[e], 1);
  if (r < CAP) {
    tok[e * CAP + r] = t;
    pb[e * CAP + r] = w[i];
  }
}

// ---------------- fp32 -> bf16 linear convert ----------------
__global__ __launch_bounds__(256) void k_conv(const float* __restrict__ src,
                                              __hip_bfloat16* __restrict__ dst, int n4) {
  int i = blockIdx.x * 256 + threadIdx.x;
  int stride = gridDim.x * 256;
  for (; i < n4; i += stride) {
    float4 v = *(const float4*)(src + (size_t)i * 4);
    *(uint2*)(dst + (size_t)i * 4) = make_uint2(pack_bf16(v.x, v.y), pack_bf16(v.z, v.w));
  }
}

// ---------------- fp32 [E][R][C] -> bf16 [E][C][R] transpose-convert ----------------
__global__ __launch_bounds__(256) void k_tconv(const float* __restrict__ src,
                                               __hip_bfloat16* __restrict__ dst,
                                               int R, int C) {
  __shared__ unsigned short s[64][88];
  int nrt = R >> 6, nct = C >> 6;
  int bid = blockIdx.x;
  int e  = bid / (nrt * nct);
  int rr = bid % (nrt * nct);
  int rt = rr / nct, ct = rr % nct;
  int r0 = rt * 64, c0 = ct * 64;
  const float* sp = src + (size_t)e * R * C;
  int t = threadIdx.x;
  int lr  = t >> 4;
  int lc4 = (t & 15) * 4;
  #pragma unroll
  for (int p = 0; p < 4; ++p) {
    int r = lr + p * 16;
    float4 v = *(const float4*)(sp + (size_t)(r0 + r) * C + c0 + lc4);
    s[lc4 + 0][r] = bf16_1(v.x);
    s[lc4 + 1][r] = bf16_1(v.y);
    s[lc4 + 2][r] = bf16_1(v.z);
    s[lc4 + 3][r] = bf16_1(v.w);
  }
  __syncthreads();
  __hip_bfloat16* dp = dst + (size_t)e * C * R;
  int wc   = t >> 2;
  int wr16 = (t & 3) * 16;
  uint4 o0 = *(const uint4*)&s[wc][wr16];
  uint4 o1 = *(const uint4*)&s[wc][wr16 + 8];
  __hip_bfloat16* o = dp + (size_t)(c0 + wc) * R + r0 + wr16;
  *(uint4*)o = o0;
  *(uint4*)(o + 8) = o1;
}

// ============ persistent 256x256 grouped GEMMs — 8-phase schedule ============
// LDS: 2 K-tile buffers x 64KB. Buffer = 4 regions of 16KB:
//   r0 = A-ks0, r1 = B-ks0, r2 = A-ks1, r3 = B-ks1   (64B rows of 32 bf16)
// Swizzle: phys 16B-chunk = logical chunk ^ ((row>>1)&3), applied to the GLOBAL
// source column (gl_lds dest stays linear) and to the ds_read address.
// Per 2 K-tiles: 8 phases {8x ds_read_b128 | 2x gl_lds (one region) | barrier |
// setprio 16 MFMA | [vmcnt(4) @ phases 4,8] barrier}. In-flight <= 12 loads.

#define STG_K(tau, r, KT, aP0, aP1, bP0, bP1)  do {                        \
    if ((tau) < (KT)) {                                                    \
      const int ko_ = (tau) * 64 + ((r) >> 1) * 32;                        \
      char* dst_ = smem + ((tau) & 1) * 65536 + (r) * 16384 + tid * 16;    \
      if (((r) & 1) == 0) {                                                \
        gl_lds16(aP0 + ko_, dst_);                                         \
        gl_lds16(aP1 + ko_, dst_ + 8192);                                  \
      } else {                                                             \
        gl_lds16(bP0 + ko_, dst_);                                         \
        gl_lds16(bP1 + ko_, dst_ + 8192);                                  \
      }                                                                    \
    }                                                                      \
  } while (0)

#define PHASE(bufb, ks, mh, STGSTMT, CHKSTMT)  do {                        \
    const char* Areg_ = smem + (bufb) + (ks) * 32768;                      \
    const char* Breg_ = Areg_ + 16384;                                     \
    short8 af_[4], bf_[4];                                                 \
    _Pragma("unroll")                                                      \
    for (int q_ = 0; q_ < 4; ++q_) {                                       \
      int m_ = wr * 128 + ((mh) * 4 + q_) * 16 + (lane & 15);              \
      af_[q_] = *(const short8*)(Areg_ + m_ * 64 + rch);                   \
    }                                                                      \
    _Pragma("unroll")                                                      \
    for (int q_ = 0; q_ < 4; ++q_) {                                       \
      int n_ = wc * 64 + q_ * 16 + (lane & 15);                            \
      bf_[q_] = *(const short8*)(Breg_ + n_ * 64 + rch);                   \
    }                                                                      \
    STGSTMT;                                                               \
    __builtin_amdgcn_s_barrier();                                          \
    __builtin_amdgcn_s_setprio(1);                                         \
    _Pragma("unroll")                                                      \
    for (int q_ = 0; q_ < 4; ++q_)                                         \
      _Pragma("unroll")                                                    \
      for (int n_ = 0; n_ < 4; ++n_)                                       \
        acc[(mh) * 4 + q_][n_] = __builtin_amdgcn_mfma_f32_16x16x32_bf16(  \
            af_[q_], bf_[n_], acc[(mh) * 4 + q_][n_], 0, 0, 0);            \
    __builtin_amdgcn_s_setprio(0);                                         \
    CHKSTMT;                                                               \
    __builtin_amdgcn_s_barrier();                                          \
  } while (0)

#define VM4  asm volatile("s_waitcnt vmcnt(4)" ::: "memory")
#define VM0  asm volatile("s_waitcnt vmcnt(0)" ::: "memory")

// GEMM1 persistent: act = GEGLU( gather(xb) @ gupT[e]^T ) * prob
__global__ __launch_bounds__(512, 1) void k_gemm1p(
    const __hip_bfloat16* __restrict__ xb, const __hip_bfloat16* __restrict__ gupT,
    const int* __restrict__ counts, const int* __restrict__ tok,
    const float* __restrict__ pb, __hip_bfloat16* __restrict__ act)
{
  __shared__ char smem[131072];
  const int NT = TWO_INTER / 256;  // 11
  const int KT = DIM / 64;         // 32
  const int xcd  = blockIdx.x & 7;
  const int slot = blockIdx.x >> 3;
  const int tid = threadIdx.x, lane = tid & 63, w = tid >> 6;
  const int wr = w >> 2, wc = w & 3;
  const int swz = ((tid & 3) ^ ((tid >> 3) & 3)) * 8;        // staging src elem offset
  const int rch = (((lane >> 4) ^ ((lane >> 1) & 3)) << 4);  // read phys-chunk byte

  int k = 0;
  for (int ei = 0; ei < 4; ++ei) {
    const int e = xcd * 4 + ei;
    int cc = counts[e]; cc = cc > CAP ? CAP : cc;
    const int mtc = (cc + 255) >> 8;
    for (int nt = 0; nt < NT; ++nt)
      for (int mt = 0; mt < mtc; ++mt, ++k) {
        if ((k & 31) != slot) continue;
        const int m0 = mt * 256, n0 = nt * 256;
        __syncthreads();

        const __hip_bfloat16* gT = gupT + (size_t)e * TWO_INTER * DIM;
        const int m1 = tid >> 2, m2 = m1 + 128;
        const __hip_bfloat16* aP0 = xb + (size_t)tok[e * CAP + m0 + m1] * DIM + swz;
        const __hip_bfloat16* aP1 = xb + (size_t)tok[e * CAP + m0 + m2] * DIM + swz;
        const __hip_bfloat16* bP0 = gT + (size_t)(n0 + m1) * DIM + swz;
        const __hip_bfloat16* bP1 = gT + (size_t)(n0 + m2) * DIM + swz;

        f32x4 acc[8][4];
        #pragma unroll
        for (int i = 0; i < 8; ++i)
          #pragma unroll
          for (int j = 0; j < 4; ++j) acc[i][j] = (f32x4){0.f, 0.f, 0.f, 0.f};

        #define STG1(tau, r) STG_K(tau, r, KT, aP0, aP1, bP0, bP1)
        // prologue: tile0 all regions + tile1 ks0
        STG1(0, 0); STG1(0, 1); STG1(0, 2); STG1(0, 3);
        STG1(1, 0); STG1(1, 1);
        VM4;
        __builtin_amdgcn_s_barrier();

        #pragma unroll 1
        for (int t = 0; t < KT; t += 2) {
          const bool more = (t + 2 < KT);
          PHASE(0,     0, 0, STG1(t + 1, 2), );
          PHASE(0,     0, 1, STG1(t + 1, 3), );
          PHASE(0,     1, 0, STG1(t + 2, 0), );
          PHASE(0,     1, 1, STG1(t + 2, 1), if (more) { VM4; } else { VM0; });
          PHASE(65536, 0, 0, STG1(t + 2, 2), );
          PHASE(65536, 0, 1, STG1(t + 2, 3), );
          PHASE(65536, 1, 0, STG1(t + 3, 0), );
          PHASE(65536, 1, 1, STG1(t + 3, 1), if (more) { VM4; });
        }
        #undef STG1

        // epilogue: GEGLU * prob -> bf16 act
        const int colp = lane & 15;
        const int rgrp = lane >> 4;
        #pragma unroll
        for (int mi = 0; mi < 8; ++mi) {
          #pragma unroll
          for (int j = 0; j < 4; ++j) {
            int rowl = wr * 128 + mi * 16 + rgrp * 4 + j;
            float prob = pb[e * CAP + m0 + rowl];
            size_t arow = (size_t)(e * CAP + m0 + rowl) * INTER;
            #pragma unroll
            for (int ni = 0; ni < 4; ++ni) {
              float v = acc[mi][ni][j];
              float other = __shfl_xor(v, 1, 64);
              if ((lane & 1) == 0) {
                float gate = fminf(v, 7.0f);
                float up   = fminf(fmaxf(other, -7.0f), 7.0f);
                float glu  = gate / (1.0f + __expf(-1.702f * gate));
                float a    = glu * (up + 1.0f) * prob;
                int nh = n0 + wc * 64 + ni * 16 + colp;
                act[arow + (nh >> 1)] = __float2bfloat16(a);
              }
            }
          }
        }
      }
  }
}

// GEMM2 persistent: out[tok] += act @ downT[e]^T
__global__ __launch_bounds__(512, 1) void k_gemm2p(
    const __hip_bfloat16* __restrict__ act, const __hip_bfloat16* __restrict__ downT,
    const int* __restrict__ counts, const int* __restrict__ tok,
    float* __restrict__ out)
{
  __shared__ char smem[131072];
  const int NT = DIM / 256;    // 8
  const int KT = INTER / 64;   // 22
  const int xcd  = blockIdx.x & 7;
  const int slot = blockIdx.x >> 3;
  const int tid = threadIdx.x, lane = tid & 63, w = tid >> 6;
  const int wr = w >> 2, wc = w & 3;
  const int swz = ((tid & 3) ^ ((tid >> 3) & 3)) * 8;
  const int rch = (((lane >> 4) ^ ((lane >> 1) & 3)) << 4);

  int k = 0;
  for (int ei = 0; ei < 4; ++ei) {
    const int e = xcd * 4 + ei;
    int cc = counts[e]; cc = cc > CAP ? CAP : cc;
    const int mtc = (cc + 255) >> 8;
    for (int nt = 0; nt < NT; ++nt)
      for (int mt = 0; mt < mtc; ++mt, ++k) {
        if ((k & 31) != slot) continue;
        const int m0 = mt * 256, n0 = nt * 256;
        __syncthreads();

        const __hip_bfloat16* dT = downT + (size_t)e * DIM * INTER;
        const int m1 = tid >> 2, m2 = m1 + 128;
        const __hip_bfloat16* aP0 = act + (size_t)(e * CAP + m0 + m1) * INTER + swz;
        const __hip_bfloat16* aP1 = act + (size_t)(e * CAP + m0 + m2) * INTER + swz;
        const __hip_bfloat16* bP0 = dT + (size_t)(n0 + m1) * INTER + swz;
        const __hip_bfloat16* bP1 = dT + (size_t)(n0 + m2) * INTER + swz;

        f32x4 acc[8][4];
        #pragma unroll
        for (int i = 0; i < 8; ++i)
          #pragma unroll
          for (int j = 0; j < 4; ++j) acc[i][j] = (f32x4){0.f, 0.f, 0.f, 0.f};

        #define STG2(tau, r) STG_K(tau, r, KT, aP0, aP1, bP0, bP1)
        STG2(0, 0); STG2(0, 1); STG2(0, 2); STG2(0, 3);
        STG2(1, 0); STG2(1, 1);
        VM4;
        __builtin_amdgcn_s_barrier();

        #pragma unroll 1
        for (int t = 0; t < KT; t += 2) {
          const bool more = (t + 2 < KT);
          PHASE(0,     0, 0, STG2(t + 1, 2), );
          PHASE(0,     0, 1, STG2(t + 1, 3), );
          PHASE(0,     1, 0, STG2(t + 2, 0), );
          PHASE(0,     1, 1, STG2(t + 2, 1), if (more) { VM4; } else { VM0; });
          PHASE(65536, 0, 0, STG2(t + 2, 2), );
          PHASE(65536, 0, 1, STG2(t + 2, 3), );
          PHASE(65536, 1, 0, STG2(t + 3, 0), );
          PHASE(65536, 1, 1, STG2(t + 3, 1), if (more) { VM4; });
        }
        #undef STG2

        const int colp = lane & 15;
        const int rgrp = lane >> 4;
        #pragma unroll
        for (int mi = 0; mi < 8; ++mi) {
          #pragma unroll
          for (int j = 0; j < 4; ++j) {
            int rowl = wr * 128 + mi * 16 + rgrp * 4 + j;
            int tkn = tok[e * CAP + m0 + rowl];
            float* orow = out + (size_t)tkn * DIM + n0;
            #pragma unroll
            for (int ni = 0; ni < 4; ++ni)
              atomicAdd(orow + wc * 64 + ni * 16 + colp, acc[mi][ni][j]);
          }
        }
      }
  }
}

// ================= launch =================

extern "C" void kernel_launch(void* const* d_in, const int* in_sizes, int n_in,
                              void* d_out, int out_size, void* d_ws, size_t ws_size,
                              hipStream_t stream) {
  const float* x     = (const float*)d_in[0];
  const int*   tmask = (const int*)d_in[1];
  const float* w     = (const float*)d_in[2];
  const int*   idx   = (const int*)d_in[3];
  const float* gup   = (const float*)d_in[4];
  const float* down  = (const float*)d_in[5];
  float* out = (float*)d_out;

  char* ws = (char*)d_ws;
  const size_t off_tok   = 256;
  const size_t off_pb    = 256 + 131072;
  const size_t off_act   = 256 + 262144;
  const size_t act_bytes = (size_t)N_EXPERTS * CAP * INTER * 2;
  const size_t off_xb    = off_act + act_bytes;
  const size_t xb_bytes  = (size_t)N_TOKENS * DIM * 2;
  const size_t off_gupT  = off_xb + xb_bytes;
  const size_t gupT_b    = (size_t)N_EXPERTS * TWO_INTER * DIM * 2;
  const size_t off_downT = off_gupT + gupT_b;

  int*   counts = (int*)ws;
  int*   tok    = (int*)(ws + off_tok);
  float* pbuf   = (float*)(ws + off_pb);
  __hip_bfloat16* act   = (__hip_bfloat16*)(ws + off_act);
  __hip_bfloat16* xb    = (__hip_bfloat16*)(ws + off_xb);
  __hip_bfloat16* gupT  = (__hip_bfloat16*)(ws + off_gupT);
  __hip_bfloat16* downT = (__hip_bfloat16*)(ws + off_downT);

  hipMemsetAsync(ws, 0, off_act, stream);
  k_build<<<(T_ASSIGN + 255) / 256, 256, 0, stream>>>(tmask, w, idx, counts, tok, pbuf);
  hipMemsetAsync(d_out, 0, (size_t)N_TOKENS * DIM * sizeof(float), stream);

  k_conv<<<2048, 256, 0, stream>>>(x, xb, (N_TOKENS * DIM) / 4);
  k_tconv<<<N_EXPERTS * (DIM / 64) * (TWO_INTER / 64), 256, 0, stream>>>(gup, gupT, DIM, TWO_INTER);
  k_tconv<<<N_EXPERTS * (INTER / 64) * (DIM / 64), 256, 0, stream>>>(down, downT, INTER, DIM);

  k_gemm1p<<<256, 512, 0, stream>>>(xb, gupT, counts, tok, pbuf, act);
  k_gemm2p<<<256, 512, 0, stream>>>(act, downT, counts, tok, out);
}

// Round 7
// 919.807 us; speedup vs baseline: 1.4147x; 1.4147x over previous
//
#include <hip/hip_runtime.h>
#include <hip/hip_bf16.h>
#include <cstdint>
#include <cstddef>

#define N_TOKENS  4096
#define DIM       2048
#define N_EXPERTS 32
#define TOPK      4
#define INTER     1408
#define TWO_INTER 2816
#define CAP       1024
#define T_ASSIGN  (N_TOKENS*TOPK)

typedef __attribute__((ext_vector_type(8))) short short8;
typedef __attribute__((ext_vector_type(4))) float f32x4;

__device__ __forceinline__ unsigned pack_bf16(float a, float b) {
  unsigned ua = __builtin_bit_cast(unsigned, a);
  unsigned ub = __builtin_bit_cast(unsigned, b);
  ua = (ua + 0x8000u) >> 16;
  ub = (ub + 0x8000u) & 0xFFFF0000u;
  return ua | ub;
}
__device__ __forceinline__ unsigned short bf16_1(float a) {
  return (unsigned short)((__builtin_bit_cast(unsigned, a) + 0x8000u) >> 16);
}

__device__ __forceinline__ void gl_lds16(const void* g, void* l) {
  __builtin_amdgcn_global_load_lds(
      (const __attribute__((address_space(1))) unsigned int*)g,
      (__attribute__((address_space(3))) unsigned int*)l, 16, 0, 0);
}

// ---------------- routing build (+ inverse map pos) ----------------
__global__ void k_build(const int* __restrict__ tmask, const float* __restrict__ w,
                        const int* __restrict__ idx, int* __restrict__ counts,
                        int* __restrict__ tok, float* __restrict__ pb,
                        int* __restrict__ pos) {
  int i = blockIdx.x * 256 + threadIdx.x;
  if (i >= T_ASSIGN) return;
  int t = i >> 2;
  int e = idx[i];
  if (e < 0 || e >= N_EXPERTS) return;
  if (tmask[t] == 0) return;
  int r = atomicAdd(&counts[e], 1);
  if (r < CAP) {
    tok[e * CAP + r] = t;
    pb[e * CAP + r] = w[i];
    pos[i] = e * CAP + r;
  }
}

// ---------------- fp32 -> bf16 linear convert ----------------
__global__ __launch_bounds__(256) void k_conv(const float* __restrict__ src,
                                              __hip_bfloat16* __restrict__ dst, int n4) {
  int i = blockIdx.x * 256 + threadIdx.x;
  int stride = gridDim.x * 256;
  for (; i < n4; i += stride) {
    float4 v = *(const float4*)(src + (size_t)i * 4);
    *(uint2*)(dst + (size_t)i * 4) = make_uint2(pack_bf16(v.x, v.y), pack_bf16(v.z, v.w));
  }
}

// ---------------- fp32 [E][R][C] -> bf16 [E][C][R] transpose-convert ----------------
__global__ __launch_bounds__(256) void k_tconv(const float* __restrict__ src,
                                               __hip_bfloat16* __restrict__ dst,
                                               int R, int C) {
  __shared__ unsigned short s[64][88];
  int nrt = R >> 6, nct = C >> 6;
  int bid = blockIdx.x;
  int e  = bid / (nrt * nct);
  int rr = bid % (nrt * nct);
  int rt = rr / nct, ct = rr % nct;
  int r0 = rt * 64, c0 = ct * 64;
  const float* sp = src + (size_t)e * R * C;
  int t = threadIdx.x;
  int lr  = t >> 4;
  int lc4 = (t & 15) * 4;
  #pragma unroll
  for (int p = 0; p < 4; ++p) {
    int r = lr + p * 16;
    float4 v = *(const float4*)(sp + (size_t)(r0 + r) * C + c0 + lc4);
    s[lc4 + 0][r] = bf16_1(v.x);
    s[lc4 + 1][r] = bf16_1(v.y);
    s[lc4 + 2][r] = bf16_1(v.z);
    s[lc4 + 3][r] = bf16_1(v.w);
  }
  __syncthreads();
  __hip_bfloat16* dp = dst + (size_t)e * C * R;
  int wc   = t >> 2;
  int wr16 = (t & 3) * 16;
  uint4 o0 = *(const uint4*)&s[wc][wr16];
  uint4 o1 = *(const uint4*)&s[wc][wr16 + 8];
  __hip_bfloat16* o = dp + (size_t)(c0 + wc) * R + r0 + wr16;
  *(uint4*)o = o0;
  *(uint4*)(o + 8) = o1;
}

// ---------------- combine: out[t] = sum_k y[pos[t][k]] ----------------
__global__ __launch_bounds__(256) void k_combine(const float* __restrict__ y,
                                                 const int* __restrict__ pos,
                                                 float* __restrict__ out) {
  int gid = blockIdx.x * 256 + threadIdx.x;     // 4096*512 float4s
  int t  = gid >> 9;                            // 512 float4 per token row
  int d4 = (gid & 511) * 4;
  int4 p = *(const int4*)(pos + t * 4);
  float4 s = make_float4(0.f, 0.f, 0.f, 0.f);
  if (p.x >= 0) { float4 v = *(const float4*)(y + (size_t)p.x * DIM + d4); s.x += v.x; s.y += v.y; s.z += v.z; s.w += v.w; }
  if (p.y >= 0) { float4 v = *(const float4*)(y + (size_t)p.y * DIM + d4); s.x += v.x; s.y += v.y; s.z += v.z; s.w += v.w; }
  if (p.z >= 0) { float4 v = *(const float4*)(y + (size_t)p.z * DIM + d4); s.x += v.x; s.y += v.y; s.z += v.z; s.w += v.w; }
  if (p.w >= 0) { float4 v = *(const float4*)(y + (size_t)p.w * DIM + d4); s.x += v.x; s.y += v.y; s.z += v.z; s.w += v.w; }
  *(float4*)(out + (size_t)t * DIM + d4) = s;
}

// ============ persistent 256x256 grouped GEMMs — 8-phase schedule ============
// LDS: 2 K-tile buffers x 64KB; buffer = 4 regions of 16KB (A0,B0,A1,B1), 64B rows.
// Swizzle: phys 16B-chunk = logical ^ ((row>>1)&3), applied on global source col
// (gl_lds dest linear) and on ds_read addr.

#define STG_K(tau, r, KT, aP0, aP1, bP0, bP1)  do {                        \
    if ((tau) < (KT)) {                                                    \
      const int ko_ = (tau) * 64 + ((r) >> 1) * 32;                        \
      char* dst_ = smem + ((tau) & 1) * 65536 + (r) * 16384 + tid * 16;    \
      if (((r) & 1) == 0) {                                                \
        gl_lds16(aP0 + ko_, dst_);                                         \
        gl_lds16(aP1 + ko_, dst_ + 8192);                                  \
      } else {                                                             \
        gl_lds16(bP0 + ko_, dst_);                                         \
        gl_lds16(bP1 + ko_, dst_ + 8192);                                  \
      }                                                                    \
    }                                                                      \
  } while (0)

#define PHASE(bufb, ks, mh, STGSTMT, CHKSTMT)  do {                        \
    const char* Areg_ = smem + (bufb) + (ks) * 32768;                      \
    const char* Breg_ = Areg_ + 16384;                                     \
    short8 af_[4], bf_[4];                                                 \
    _Pragma("unroll")                                                      \
    for (int q_ = 0; q_ < 4; ++q_) {                                       \
      int m_ = wr * 128 + ((mh) * 4 + q_) * 16 + (lane & 15);              \
      af_[q_] = *(const short8*)(Areg_ + m_ * 64 + rch);                   \
    }                                                                      \
    _Pragma("unroll")                                                      \
    for (int q_ = 0; q_ < 4; ++q_) {                                       \
      int n_ = wc * 64 + q_ * 16 + (lane & 15);                            \
      bf_[q_] = *(const short8*)(Breg_ + n_ * 64 + rch);                   \
    }                                                                      \
    STGSTMT;                                                               \
    __builtin_amdgcn_s_barrier();                                          \
    __builtin_amdgcn_s_setprio(1);                                         \
    _Pragma("unroll")                                                      \
    for (int q_ = 0; q_ < 4; ++q_)                                         \
      _Pragma("unroll")                                                    \
      for (int n_ = 0; n_ < 4; ++n_)                                       \
        acc[(mh) * 4 + q_][n_] = __builtin_amdgcn_mfma_f32_16x16x32_bf16(  \
            af_[q_], bf_[n_], acc[(mh) * 4 + q_][n_], 0, 0, 0);            \
    __builtin_amdgcn_s_setprio(0);                                         \
    CHKSTMT;                                                               \
    __builtin_amdgcn_s_barrier();                                          \
  } while (0)

#define VM4  asm volatile("s_waitcnt vmcnt(4)" ::: "memory")
#define VM0  asm volatile("s_waitcnt vmcnt(0)" ::: "memory")

// GEMM1 persistent: act = GEGLU( gather(xb) @ gupT[e]^T ) * prob
__global__ __launch_bounds__(512, 1) void k_gemm1p(
    const __hip_bfloat16* __restrict__ xb, const __hip_bfloat16* __restrict__ gupT,
    const int* __restrict__ counts, const int* __restrict__ tok,
    const float* __restrict__ pb, __hip_bfloat16* __restrict__ act)
{
  __shared__ char smem[131072];
  const int NT = TWO_INTER / 256;  // 11
  const int KT = DIM / 64;         // 32
  const int xcd  = blockIdx.x & 7;
  const int slot = blockIdx.x >> 3;
  const int tid = threadIdx.x, lane = tid & 63, w = tid >> 6;
  const int wr = w >> 2, wc = w & 3;
  const int swz = ((tid & 3) ^ ((tid >> 3) & 3)) * 8;
  const int rch = (((lane >> 4) ^ ((lane >> 1) & 3)) << 4);

  int k = 0;
  for (int ei = 0; ei < 4; ++ei) {
    const int e = xcd * 4 + ei;
    int cc = counts[e]; cc = cc > CAP ? CAP : cc;
    const int mtc = (cc + 255) >> 8;
    for (int nt = 0; nt < NT; ++nt)
      for (int mt = 0; mt < mtc; ++mt, ++k) {
        if ((k & 31) != slot) continue;
        const int m0 = mt * 256, n0 = nt * 256;
        __syncthreads();

        const __hip_bfloat16* gT = gupT + (size_t)e * TWO_INTER * DIM;
        const int m1 = tid >> 2, m2 = m1 + 128;
        const __hip_bfloat16* aP0 = xb + (size_t)tok[e * CAP + m0 + m1] * DIM + swz;
        const __hip_bfloat16* aP1 = xb + (size_t)tok[e * CAP + m0 + m2] * DIM + swz;
        const __hip_bfloat16* bP0 = gT + (size_t)(n0 + m1) * DIM + swz;
        const __hip_bfloat16* bP1 = gT + (size_t)(n0 + m2) * DIM + swz;

        f32x4 acc[8][4];
        #pragma unroll
        for (int i = 0; i < 8; ++i)
          #pragma unroll
          for (int j = 0; j < 4; ++j) acc[i][j] = (f32x4){0.f, 0.f, 0.f, 0.f};

        #define STG1(tau, r) STG_K(tau, r, KT, aP0, aP1, bP0, bP1)
        STG1(0, 0); STG1(0, 1); STG1(0, 2); STG1(0, 3);
        STG1(1, 0); STG1(1, 1);
        VM4;
        __builtin_amdgcn_s_barrier();

        #pragma unroll 1
        for (int t = 0; t < KT; t += 2) {
          const bool more = (t + 2 < KT);
          PHASE(0,     0, 0, STG1(t + 1, 2), );
          PHASE(0,     0, 1, STG1(t + 1, 3), );
          PHASE(0,     1, 0, STG1(t + 2, 0), );
          PHASE(0,     1, 1, STG1(t + 2, 1), if (more) { VM4; } else { VM0; });
          PHASE(65536, 0, 0, STG1(t + 2, 2), );
          PHASE(65536, 0, 1, STG1(t + 2, 3), );
          PHASE(65536, 1, 0, STG1(t + 3, 0), );
          PHASE(65536, 1, 1, STG1(t + 3, 1), if (more) { VM4; });
        }
        #undef STG1

        const int colp = lane & 15;
        const int rgrp = lane >> 4;
        #pragma unroll
        for (int mi = 0; mi < 8; ++mi) {
          #pragma unroll
          for (int j = 0; j < 4; ++j) {
            int rowl = wr * 128 + mi * 16 + rgrp * 4 + j;
            float prob = pb[e * CAP + m0 + rowl];
            size_t arow = (size_t)(e * CAP + m0 + rowl) * INTER;
            #pragma unroll
            for (int ni = 0; ni < 4; ++ni) {
              float v = acc[mi][ni][j];
              float other = __shfl_xor(v, 1, 64);
              if ((lane & 1) == 0) {
                float gate = fminf(v, 7.0f);
                float up   = fminf(fmaxf(other, -7.0f), 7.0f);
                float glu  = gate / (1.0f + __expf(-1.702f * gate));
                float a    = glu * (up + 1.0f) * prob;
                int nh = n0 + wc * 64 + ni * 16 + colp;
                act[arow + (nh >> 1)] = __float2bfloat16(a);
              }
            }
          }
        }
      }
  }
}

// GEMM2 persistent: y[slot] = act @ downT[e]^T   (plain stores, no atomics)
__global__ __launch_bounds__(512, 1) void k_gemm2p(
    const __hip_bfloat16* __restrict__ act, const __hip_bfloat16* __restrict__ downT,
    const int* __restrict__ counts, float* __restrict__ y)
{
  __shared__ char smem[131072];
  const int NT = DIM / 256;    // 8
  const int KT = INTER / 64;   // 22
  const int xcd  = blockIdx.x & 7;
  const int slot = blockIdx.x >> 3;
  const int tid = threadIdx.x, lane = tid & 63, w = tid >> 6;
  const int wr = w >> 2, wc = w & 3;
  const int swz = ((tid & 3) ^ ((tid >> 3) & 3)) * 8;
  const int rch = (((lane >> 4) ^ ((lane >> 1) & 3)) << 4);

  int k = 0;
  for (int ei = 0; ei < 4; ++ei) {
    const int e = xcd * 4 + ei;
    int cc = counts[e]; cc = cc > CAP ? CAP : cc;
    const int mtc = (cc + 255) >> 8;
    for (int nt = 0; nt < NT; ++nt)
      for (int mt = 0; mt < mtc; ++mt, ++k) {
        if ((k & 31) != slot) continue;
        const int m0 = mt * 256, n0 = nt * 256;
        __syncthreads();

        const __hip_bfloat16* dT = downT + (size_t)e * DIM * INTER;
        const int m1 = tid >> 2, m2 = m1 + 128;
        const __hip_bfloat16* aP0 = act + (size_t)(e * CAP + m0 + m1) * INTER + swz;
        const __hip_bfloat16* aP1 = act + (size_t)(e * CAP + m0 + m2) * INTER + swz;
        const __hip_bfloat16* bP0 = dT + (size_t)(n0 + m1) * INTER + swz;
        const __hip_bfloat16* bP1 = dT + (size_t)(n0 + m2) * INTER + swz;

        f32x4 acc[8][4];
        #pragma unroll
        for (int i = 0; i < 8; ++i)
          #pragma unroll
          for (int j = 0; j < 4; ++j) acc[i][j] = (f32x4){0.f, 0.f, 0.f, 0.f};

        #define STG2(tau, r) STG_K(tau, r, KT, aP0, aP1, bP0, bP1)
        STG2(0, 0); STG2(0, 1); STG2(0, 2); STG2(0, 3);
        STG2(1, 0); STG2(1, 1);
        VM4;
        __builtin_amdgcn_s_barrier();

        #pragma unroll 1
        for (int t = 0; t < KT; t += 2) {
          const bool more = (t + 2 < KT);
          PHASE(0,     0, 0, STG2(t + 1, 2), );
          PHASE(0,     0, 1, STG2(t + 1, 3), );
          PHASE(0,     1, 0, STG2(t + 2, 0), );
          PHASE(0,     1, 1, STG2(t + 2, 1), if (more) { VM4; } else { VM0; });
          PHASE(65536, 0, 0, STG2(t + 2, 2), );
          PHASE(65536, 0, 1, STG2(t + 2, 3), );
          PHASE(65536, 1, 0, STG2(t + 3, 0), );
          PHASE(65536, 1, 1, STG2(t + 3, 1), if (more) { VM4; });
        }
        #undef STG2

        const int colp = lane & 15;
        const int rgrp = lane >> 4;
        #pragma unroll
        for (int mi = 0; mi < 8; ++mi) {
          #pragma unroll
          for (int j = 0; j < 4; ++j) {
            int rowl = wr * 128 + mi * 16 + rgrp * 4 + j;
            float* yrow = y + (size_t)(e * CAP + m0 + rowl) * DIM + n0;
            #pragma unroll
            for (int ni = 0; ni < 4; ++ni)
              yrow[wc * 64 + ni * 16 + colp] = acc[mi][ni][j];
          }
        }
      }
  }
}

// ================= launch =================

extern "C" void kernel_launch(void* const* d_in, const int* in_sizes, int n_in,
                              void* d_out, int out_size, void* d_ws, size_t ws_size,
                              hipStream_t stream) {
  const float* x     = (const float*)d_in[0];
  const int*   tmask = (const int*)d_in[1];
  const float* w     = (const float*)d_in[2];
  const int*   idx   = (const int*)d_in[3];
  const float* gup   = (const float*)d_in[4];
  const float* down  = (const float*)d_in[5];
  float* out = (float*)d_out;

  char* ws = (char*)d_ws;
  const size_t off_tok   = 256;
  const size_t off_pb    = off_tok + 131072;         // 131328
  const size_t off_pos   = off_pb + 131072;          // 262400
  const size_t off_act   = off_pos + 65536;          // 327936
  const size_t act_bytes = (size_t)N_EXPERTS * CAP * INTER * 2;
  const size_t off_xb    = off_act + act_bytes;
  const size_t xb_bytes  = (size_t)N_TOKENS * DIM * 2;
  const size_t off_gupT  = off_xb + xb_bytes;
  const size_t gupT_b    = (size_t)N_EXPERTS * TWO_INTER * DIM * 2;
  const size_t off_downT = off_gupT + gupT_b;

  int*   counts = (int*)ws;
  int*   tok    = (int*)(ws + off_tok);
  float* pbuf   = (float*)(ws + off_pb);
  int*   pos    = (int*)(ws + off_pos);
  __hip_bfloat16* act   = (__hip_bfloat16*)(ws + off_act);
  __hip_bfloat16* xb    = (__hip_bfloat16*)(ws + off_xb);
  __hip_bfloat16* gupT  = (__hip_bfloat16*)(ws + off_gupT);
  __hip_bfloat16* downT = (__hip_bfloat16*)(ws + off_downT);
  float* y = (float*)(ws + off_gupT);  // reuse gupT region (idle during gemm2): 268MB <= 369MB

  hipMemsetAsync(ws, 0, off_pos, stream);
  hipMemsetAsync(ws + off_pos, 0xFF, 65536, stream);  // pos = -1
  k_build<<<(T_ASSIGN + 255) / 256, 256, 0, stream>>>(tmask, w, idx, counts, tok, pbuf, pos);

  k_conv<<<2048, 256, 0, stream>>>(x, xb, (N_TOKENS * DIM) / 4);
  k_tconv<<<N_EXPERTS * (DIM / 64) * (TWO_INTER / 64), 256, 0, stream>>>(gup, gupT, DIM, TWO_INTER);
  k_tconv<<<N_EXPERTS * (INTER / 64) * (DIM / 64), 256, 0, stream>>>(down, downT, INTER, DIM);

  k_gemm1p<<<256, 512, 0, stream>>>(xb, gupT, counts, tok, pbuf, act);
  k_gemm2p<<<256, 512, 0, stream>>>(act, downT, counts, y);
  k_combine<<<(N_TOKENS * DIM / 4) / 256, 256, 0, stream>>>(y, pos, out);
}